// Round 1
// 259.396 us; speedup vs baseline: 1.0292x; 1.0292x over previous
//
#include <hip/hip_runtime.h>

// ---------------------------------------------------------------------------
// PointTransformerForSegmentation, round 6 restructure:
//   convert   : bf16-cast w0feat / w0pos / w1 / feat2
//   fgemm     : F[b*128+n2][512] = feat2 . W0feat^T   (f32, tiny GEMM)
//   build_h0  : kNN + pos embed + (K=32 MFMA pos.W0pos^T) + F gather
//               -> H0 plane-major [j][query][512] bf16  (NO pad rows)
//   gemm2     : per 128x128 tile, 3 K-passes (j planes) with
//               sum += relu(acc*s1+b1) folded in registers -> out (B,H1,N1)
// LDS layout for all GEMMs: fragment-linear 16-row groups (chunk-major),
// lane l reads group*1024 + l*16 -> sequential banks, zero conflicts.
// ---------------------------------------------------------------------------

typedef unsigned short u16;
typedef __bf16 bf16x8 __attribute__((ext_vector_type(8)));
typedef float f32x4 __attribute__((ext_vector_type(4)));
typedef u16 u16x4 __attribute__((ext_vector_type(4)));

#define BQ 8
#define N1Q 2048
#define N2Q 128
#define C2Q 256
#define DPOS 32
#define H0Q 512
#define H1Q 1024
#define NQ (BQ * N1Q)   // 16384 queries

// workspace layout (bytes)
#define WS_W0F 0u          // 512*256*2   = 262144
#define WS_W0P 262144u     // 512*32*2    = 32768
#define WS_W1 294912u      // 1024*512*2  = 1048576
#define WS_F2B 1343488u    // 1024*256*2  = 524288
#define WS_F 1867776u      // 1024*512*4  = 2097152
#define WS_H0 3964928u     // 3*16384*512*2 = 50331648 (end 54296576)

__device__ __forceinline__ u16 f2bf(float f) {
  unsigned int u = __builtin_bit_cast(unsigned int, f);
  return (u16)((u + 0x7FFFu + ((u >> 16) & 1u)) >> 16);
}

__device__ __forceinline__ void load16_lds(const void* g, void* l) {
  __builtin_amdgcn_global_load_lds(
      (const __attribute__((address_space(1))) unsigned int*)g,
      (__attribute__((address_space(3))) unsigned int*)l, 16, 0, 0);
}

// ---------------------------------------------------------------------------
// convert: w0feat (512x256), w0pos (512x32), w1 (1024x512), feat2 (1024x256)
__global__ void convert_inputs(const float* __restrict__ w0,
                               const float* __restrict__ w1,
                               const float* __restrict__ feat2,
                               u16* __restrict__ w0f, u16* __restrict__ w0p,
                               u16* __restrict__ w1b, u16* __restrict__ f2b) {
  int i = blockIdx.x * 256 + threadIdx.x;  // grid covers 933888 exactly
  if (i < 131072) {
    int h = i >> 8, c = i & 255;
    w0f[i] = f2bf(w0[h * 288 + c]);
  } else if (i < 147456) {
    int j = i - 131072;
    int h = j >> 5, c = j & 31;
    w0p[j] = f2bf(w0[h * 288 + 256 + c]);
  } else if (i < 671744) {
    int j = i - 147456;
    w1b[j] = f2bf(w1[j]);
  } else {
    int j = i - 671744;  // < 262144
    f2b[j] = f2bf(feat2[j]);
  }
}

// ---------------------------------------------------------------------------
// fgemm: F[m][n] = sum_k feat2bf[m][k]*w0featbf[n][k], f32 out.
// M=1024 N=512 K=256, 128x128 tile, 32 blocks.
__global__ __launch_bounds__(256, 2) void fgemm(const u16* __restrict__ A,
                                                const u16* __restrict__ W,
                                                float* __restrict__ F) {
  __shared__ alignas(16) u16 As[128 * 32];
  __shared__ alignas(16) u16 Bs[128 * 32];
  const int m0 = (blockIdx.x >> 2) * 128, n0 = (blockIdx.x & 3) * 128;
  const int t = threadIdx.x;
  const int wv = t >> 6, lane = t & 63;
  const int wm = wv >> 1, wn = wv & 1;
  const int quad = lane >> 4, cc = lane & 15;
  const int srow = lane & 15, skc = quad * 8;
  f32x4 acc[4][4] = {};

  for (int k0 = 0; k0 < 256; k0 += 32) {
#pragma unroll
    for (int i = 0; i < 2; i++) {
      int g = i * 4 + wv;
      load16_lds(A + (size_t)(m0 + g * 16 + srow) * 256 + k0 + skc,
                 (char*)As + g * 1024 + (lane << 4));
      load16_lds(W + (size_t)(n0 + g * 16 + srow) * 256 + k0 + skc,
                 (char*)Bs + g * 1024 + (lane << 4));
    }
    __syncthreads();
    bf16x8 af[4], bf[4];
#pragma unroll
    for (int mt = 0; mt < 4; mt++)
      af[mt] = *(const bf16x8*)((const char*)As + (wm * 4 + mt) * 1024 + (lane << 4));
#pragma unroll
    for (int nt = 0; nt < 4; nt++)
      bf[nt] = *(const bf16x8*)((const char*)Bs + (wn * 4 + nt) * 1024 + (lane << 4));
#pragma unroll
    for (int mt = 0; mt < 4; mt++)
#pragma unroll
      for (int nt = 0; nt < 4; nt++)
        acc[mt][nt] = __builtin_amdgcn_mfma_f32_16x16x32_bf16(
            af[mt], bf[nt], acc[mt][nt], 0, 0, 0);
    __syncthreads();
  }

#pragma unroll
  for (int nt = 0; nt < 4; nt++) {
    int gn = n0 + wn * 64 + nt * 16 + cc;
#pragma unroll
    for (int mt = 0; mt < 4; mt++) {
      int gm = m0 + wm * 64 + mt * 16 + quad * 4;
#pragma unroll
      for (int r = 0; r < 4; r++)
        F[(size_t)(gm + r) * H0Q + gn] = acc[mt][nt][r];
    }
  }
}

// ---------------------------------------------------------------------------
// build_h0: block = 64 queries (256 blocks). Phase1: kNN + pos (bf16, stored
// fragment-linear in LDS). Phase2: G = pos.W0pos^T via MFMA with SWAPPED
// operands (C: col=query-row, row=h) so F-gather / s0 / b0 / H0-store are all
// f32x4 / u16x4 vector ops. H0 row = j*16384 + query (plane-major, no pads).
__global__ __launch_bounds__(256, 2) void build_h0(
    const float* __restrict__ xyz1, const float* __restrict__ xyz2,
    const float* __restrict__ lrf2, const float* __restrict__ w_pos,
    const float* __restrict__ pscale, const float* __restrict__ pbias,
    const u16* __restrict__ w0p, const float* __restrict__ F,
    const float* __restrict__ s0, const float* __restrict__ b0,
    u16* __restrict__ H0) {
  __shared__ float xyz2s[N2Q * 3];
  __shared__ float n2s[N2Q];
  __shared__ float lrfs[N2Q * 9];
  __shared__ float wps[DPOS * 4];
  __shared__ float pss[DPOS];
  __shared__ float pbs[DPOS];
  __shared__ int idxb[192];
  __shared__ alignas(16) u16 posb[12 * 512];  // 12 groups x (16 rows x 32) lane-linear

  const int t = threadIdx.x;
  const int qb = blockIdx.x * 64;
  const int b = qb >> 11;

  for (int i = t; i < N2Q * 3; i += 256) xyz2s[i] = xyz2[b * N2Q * 3 + i];
  for (int i = t; i < N2Q * 9; i += 256) lrfs[i] = lrf2[b * N2Q * 9 + i];
  if (t < DPOS * 4) wps[t] = w_pos[t];
  if (t < DPOS) { pss[t] = pscale[t]; pbs[t] = pbias[t]; }
  __syncthreads();
  if (t < N2Q) {
    float x = xyz2s[t * 3], y = xyz2s[t * 3 + 1], z = xyz2s[t * 3 + 2];
    n2s[t] = x * x + y * y + z * z;
  }
  __syncthreads();

  // ---- phase 1: kNN + pos embed, one thread per query ----
  if (t < 64) {
    const int q = qb + t;
    const float px = xyz1[q * 3], py = xyz1[q * 3 + 1], pz = xyz1[q * 3 + 2];
    const float pn = px * px + py * py + pz * pz;
    float d0 = 1e30f, d1 = 1e30f, d2v = 1e30f;
    int i0 = 0, i1 = 0, i2 = 0;
    for (int i = 0; i < N2Q; i++) {
      float dt = px * xyz2s[i * 3] + py * xyz2s[i * 3 + 1] + pz * xyz2s[i * 3 + 2];
      float d = pn + n2s[i] - 2.f * dt;
      if (d < d0) {
        d2v = d1; i2 = i1; d1 = d0; i1 = i0; d0 = d; i0 = i;
      } else if (d < d1) {
        d2v = d1; i2 = i1; d1 = d; i1 = i;
      } else if (d < d2v) {
        d2v = d; i2 = i;
      }
    }
    int sel0 = i0, sel1 = i1, sel2 = i2;
#pragma unroll
    for (int j = 0; j < 3; j++) {
      int id = (j == 0) ? sel0 : (j == 1) ? sel1 : sel2;
      float rx = px - xyz2s[id * 3];
      float ry = py - xyz2s[id * 3 + 1];
      float rz = pz - xyz2s[id * 3 + 2];
      float rn = sqrtf(rx * rx + ry * ry + rz * rz);
      float inv = 1.f / fmaxf(rn, 1e-12f);
      float ux = rx * inv, uy = ry * inv, uz = rz * inv;
      const float* L = lrfs + id * 9;
      float a0 = L[0] * ux + L[1] * uy + L[2] * uz;
      float a1 = L[3] * ux + L[4] * uy + L[5] * uz;
      float a2 = L[6] * ux + L[7] * uy + L[8] * uz;
      int row = j * 64 + t;
      idxb[row] = id;
      u16* pd = posb + (row >> 4) * 512 + (row & 15) * 8;
#pragma unroll
      for (int o = 0; o < 32; o++) {
        float v = wps[o * 4] * rn + wps[o * 4 + 1] * a0 + wps[o * 4 + 2] * a1 +
                  wps[o * 4 + 3] * a2;
        v = v * pss[o] + pbs[o];
        v = (v >= 0.f) ? v : 0.2f * v;  // LeakyReLU(0.2)
        pd[(o >> 3) * 128 + (o & 7)] = f2bf(v);
      }
    }
  }
  __syncthreads();

  // ---- phase 2: H0 = relu((F[idx] + pos.W0pos^T)*s0 + b0) ----
  const int wv = t >> 6, lane = t & 63;
  const int quad = lane >> 4, cc = lane & 15;
  int idxm[3];
  const float* Fr[3];
  u16* Hr[3];
#pragma unroll
  for (int mt = 0; mt < 3; mt++) {
    int rl = wv * 48 + mt * 16 + cc;  // wave's rows: groups 3*wv+mt
    idxm[mt] = idxb[rl];
    Fr[mt] = F + ((size_t)(b * N2Q + idxm[mt])) * H0Q;
    int jj = rl >> 6, ql = rl & 63;
    Hr[mt] = H0 + ((size_t)(jj * NQ) + qb + ql) * H0Q;
  }
  bf16x8 afr[3];
#pragma unroll
  for (int mt = 0; mt < 3; mt++)
    afr[mt] = *(const bf16x8*)((const char*)posb + (wv * 3 + mt) * 1024 + (lane << 4));
  const f32x4 zf = {};
  for (int n0 = 0; n0 < H0Q; n0 += 128) {
    bf16x8 bfr[8];
#pragma unroll
    for (int nt = 0; nt < 8; nt++)
      bfr[nt] = *(const bf16x8*)(w0p + (n0 + nt * 16 + cc) * 32 + quad * 8);
    f32x4 acc[3][8];
#pragma unroll
    for (int mt = 0; mt < 3; mt++)
#pragma unroll
      for (int nt = 0; nt < 8; nt++)  // swapped operands: C row=h, col=query
        acc[mt][nt] = __builtin_amdgcn_mfma_f32_16x16x32_bf16(bfr[nt], afr[mt],
                                                              zf, 0, 0, 0);
#pragma unroll
    for (int nt = 0; nt < 8; nt++) {
      int hb = n0 + nt * 16 + quad * 4;
      f32x4 sv = *(const f32x4*)(s0 + hb);
      f32x4 bvv = *(const f32x4*)(b0 + hb);
#pragma unroll
      for (int mt = 0; mt < 3; mt++) {
        f32x4 fv = *(const f32x4*)(Fr[mt] + hb);
        u16x4 o4;
#pragma unroll
        for (int r = 0; r < 4; r++) {
          float h = (fv[r] + acc[mt][nt][r]) * sv[r] + bvv[r];
          h = h > 0.f ? h : 0.f;
          o4[r] = f2bf(h);
        }
        *(u16x4*)(Hr[mt] + hb) = o4;
      }
    }
  }
}

// ---------------------------------------------------------------------------
// gemm2: out[b][n][n1] = sum_j relu((H0_j[q][:] . W1[n][:])*s1[n] + b1[n]).
// M=16384 (queries), N=1024, K=512 x 3 planes. 128x128 tile, 1024 blocks,
// XCD-partitioned m-tiles. Fragment-linear LDS, 3-pass register accumulation.
__global__ __launch_bounds__(256, 2) void gemm2(const u16* __restrict__ A,
                                                const u16* __restrict__ W,
                                                const float* __restrict__ s,
                                                const float* __restrict__ bz,
                                                float* __restrict__ out) {
  __shared__ alignas(16) u16 As[128 * 32];
  __shared__ alignas(16) u16 Bs[128 * 32];
  const int id = blockIdx.x;            // 1024 blocks
  const int xcd = id & 7, g = id >> 3;  // g 0..127
  const int m0 = (xcd * 16 + (g >> 3)) * 128;  // 16 m-tiles per XCD
  const int n0 = (g & 7) * 128;
  const int t = threadIdx.x;
  const int wv = t >> 6, lane = t & 63;
  const int wm = wv >> 1, wn = wv & 1;
  const int quad = lane >> 4, cc = lane & 15;
  const int srow = lane & 15, skc = quad * 8;

  float sv[4], bv[4];
#pragma unroll
  for (int nt = 0; nt < 4; nt++) {
    int gn = n0 + wn * 64 + nt * 16 + cc;
    sv[nt] = s[gn];
    bv[nt] = bz[gn];
  }
  f32x4 sum[4][4] = {};

  for (int j = 0; j < 3; j++) {
    const u16* Aj = A + (size_t)j * (NQ * H0Q) + (size_t)m0 * H0Q;
    f32x4 acc[4][4] = {};
    for (int k0 = 0; k0 < 512; k0 += 32) {
#pragma unroll
      for (int i = 0; i < 2; i++) {
        int g2 = i * 4 + wv;
        load16_lds(Aj + (size_t)(g2 * 16 + srow) * 512 + k0 + skc,
                   (char*)As + g2 * 1024 + (lane << 4));
        load16_lds(W + (size_t)(n0 + g2 * 16 + srow) * 512 + k0 + skc,
                   (char*)Bs + g2 * 1024 + (lane << 4));
      }
      __syncthreads();
      bf16x8 af[4], bf[4];
#pragma unroll
      for (int mt = 0; mt < 4; mt++)
        af[mt] = *(const bf16x8*)((const char*)As + (wm * 4 + mt) * 1024 + (lane << 4));
#pragma unroll
      for (int nt = 0; nt < 4; nt++)
        bf[nt] = *(const bf16x8*)((const char*)Bs + (wn * 4 + nt) * 1024 + (lane << 4));
#pragma unroll
      for (int mt = 0; mt < 4; mt++)
#pragma unroll
        for (int nt = 0; nt < 4; nt++)
          acc[mt][nt] = __builtin_amdgcn_mfma_f32_16x16x32_bf16(
              af[mt], bf[nt], acc[mt][nt], 0, 0, 0);
      __syncthreads();
    }
#pragma unroll
    for (int mt = 0; mt < 4; mt++)
#pragma unroll
      for (int nt = 0; nt < 4; nt++)
#pragma unroll
        for (int r = 0; r < 4; r++) {
          float h = acc[mt][nt][r] * sv[nt] + bv[nt];
          sum[mt][nt][r] += (h > 0.f ? h : 0.f);
        }
  }

#pragma unroll
  for (int nt = 0; nt < 4; nt++) {
    int gn = n0 + wn * 64 + nt * 16 + cc;
#pragma unroll
    for (int mt = 0; mt < 4; mt++) {
      int gm = m0 + wm * 64 + mt * 16 + quad * 4;
#pragma unroll
      for (int r = 0; r < 4; r++) {
        int q = gm + r;
        out[((size_t)(q >> 11) * H1Q + gn) * N1Q + (q & 2047)] = sum[mt][nt][r];
      }
    }
  }
}

// ---------------------------------------------------------------------------
extern "C" void kernel_launch(void* const* d_in, const int* in_sizes, int n_in,
                              void* d_out, int out_size, void* d_ws,
                              size_t ws_size, hipStream_t stream) {
  const float* xyz1 = (const float*)d_in[0];
  const float* xyz2 = (const float*)d_in[1];
  const float* feat2 = (const float*)d_in[2];
  const float* lrf2 = (const float*)d_in[3];
  const float* w_pos = (const float*)d_in[4];
  const float* pscale = (const float*)d_in[5];
  const float* pbias = (const float*)d_in[6];
  const float* w0 = (const float*)d_in[7];
  const float* s0 = (const float*)d_in[8];
  const float* b0 = (const float*)d_in[9];
  const float* w1 = (const float*)d_in[10];
  const float* s1 = (const float*)d_in[11];
  const float* b1 = (const float*)d_in[12];
  float* out = (float*)d_out;

  char* ws = (char*)d_ws;
  u16* w0f = (u16*)(ws + WS_W0F);
  u16* w0p = (u16*)(ws + WS_W0P);
  u16* w1b = (u16*)(ws + WS_W1);
  u16* f2b = (u16*)(ws + WS_F2B);
  float* F = (float*)(ws + WS_F);
  u16* H0 = (u16*)(ws + WS_H0);

  convert_inputs<<<933888 / 256, 256, 0, stream>>>(w0, w1, feat2, w0f, w0p,
                                                   w1b, f2b);
  fgemm<<<32, 256, 0, stream>>>(f2b, w0f, F);
  build_h0<<<NQ / 64, 256, 0, stream>>>(xyz1, xyz2, lrf2, w_pos, pscale,
                                        pbias, w0p, F, s0, b0, H0);
  gemm2<<<1024, 256, 0, stream>>>(H0, w1b, s1, b1, out);
}

// Round 2
// 253.635 us; speedup vs baseline: 1.0526x; 1.0227x over previous
//
#include <hip/hip_runtime.h>

// ---------------------------------------------------------------------------
// PointTransformerForSegmentation, round 7:
//   convert   : bf16-cast w0feat / w0pos / w1 / feat2
//   fgemm     : F[b*128+n2][512] = feat2 . W0feat^T   (f32, tiny GEMM)
//   build_h0  : kNN (4-way parallel scan + merge) + pos embed (192 thr) +
//               K=32 MFMA pos.W0pos^T + F gather -> H0 plane-major bf16
//   gemm2     : 2-phase software-pipelined (double-buffered LDS, stage
//               next K-step before compute, ONE barrier/step), 3 j-planes
//               flattened into one 48-step loop, relu-fold at boundaries.
// LDS layout for all GEMMs: fragment-linear 16-row groups (chunk-major),
// lane l reads group*1024 + l*16 -> sequential banks, zero conflicts.
// ---------------------------------------------------------------------------

typedef unsigned short u16;
typedef __bf16 bf16x8 __attribute__((ext_vector_type(8)));
typedef float f32x4 __attribute__((ext_vector_type(4)));
typedef u16 u16x4 __attribute__((ext_vector_type(4)));

#define BQ 8
#define N1Q 2048
#define N2Q 128
#define C2Q 256
#define DPOS 32
#define H0Q 512
#define H1Q 1024
#define NQ (BQ * N1Q)   // 16384 queries

// workspace layout (bytes)
#define WS_W0F 0u          // 512*256*2   = 262144
#define WS_W0P 262144u     // 512*32*2    = 32768
#define WS_W1 294912u      // 1024*512*2  = 1048576
#define WS_F2B 1343488u    // 1024*256*2  = 524288
#define WS_F 1867776u      // 1024*512*4  = 2097152
#define WS_H0 3964928u     // 3*16384*512*2 = 50331648 (end 54296576)

__device__ __forceinline__ u16 f2bf(float f) {
  unsigned int u = __builtin_bit_cast(unsigned int, f);
  return (u16)((u + 0x7FFFu + ((u >> 16) & 1u)) >> 16);
}

__device__ __forceinline__ void load16_lds(const void* g, void* l) {
  __builtin_amdgcn_global_load_lds(
      (const __attribute__((address_space(1))) unsigned int*)g,
      (__attribute__((address_space(3))) unsigned int*)l, 16, 0, 0);
}

// ---------------------------------------------------------------------------
// convert: w0feat (512x256), w0pos (512x32), w1 (1024x512), feat2 (1024x256)
__global__ void convert_inputs(const float* __restrict__ w0,
                               const float* __restrict__ w1,
                               const float* __restrict__ feat2,
                               u16* __restrict__ w0f, u16* __restrict__ w0p,
                               u16* __restrict__ w1b, u16* __restrict__ f2b) {
  int i = blockIdx.x * 256 + threadIdx.x;  // grid covers 933888 exactly
  if (i < 131072) {
    int h = i >> 8, c = i & 255;
    w0f[i] = f2bf(w0[h * 288 + c]);
  } else if (i < 147456) {
    int j = i - 131072;
    int h = j >> 5, c = j & 31;
    w0p[j] = f2bf(w0[h * 288 + 256 + c]);
  } else if (i < 671744) {
    int j = i - 147456;
    w1b[j] = f2bf(w1[j]);
  } else {
    int j = i - 671744;  // < 262144
    f2b[j] = f2bf(feat2[j]);
  }
}

// ---------------------------------------------------------------------------
// fgemm: F[m][n] = sum_k feat2bf[m][k]*w0featbf[n][k], f32 out.
// M=1024 N=512 K=256, 128x128 tile, 32 blocks.
__global__ __launch_bounds__(256, 2) void fgemm(const u16* __restrict__ A,
                                                const u16* __restrict__ W,
                                                float* __restrict__ F) {
  __shared__ alignas(16) u16 As[128 * 32];
  __shared__ alignas(16) u16 Bs[128 * 32];
  const int m0 = (blockIdx.x >> 2) * 128, n0 = (blockIdx.x & 3) * 128;
  const int t = threadIdx.x;
  const int wv = t >> 6, lane = t & 63;
  const int wm = wv >> 1, wn = wv & 1;
  const int quad = lane >> 4, cc = lane & 15;
  const int srow = lane & 15, skc = quad * 8;
  f32x4 acc[4][4] = {};

  for (int k0 = 0; k0 < 256; k0 += 32) {
#pragma unroll
    for (int i = 0; i < 2; i++) {
      int g = i * 4 + wv;
      load16_lds(A + (size_t)(m0 + g * 16 + srow) * 256 + k0 + skc,
                 (char*)As + g * 1024 + (lane << 4));
      load16_lds(W + (size_t)(n0 + g * 16 + srow) * 256 + k0 + skc,
                 (char*)Bs + g * 1024 + (lane << 4));
    }
    __syncthreads();
    bf16x8 af[4], bf[4];
#pragma unroll
    for (int mt = 0; mt < 4; mt++)
      af[mt] = *(const bf16x8*)((const char*)As + (wm * 4 + mt) * 1024 + (lane << 4));
#pragma unroll
    for (int nt = 0; nt < 4; nt++)
      bf[nt] = *(const bf16x8*)((const char*)Bs + (wn * 4 + nt) * 1024 + (lane << 4));
#pragma unroll
    for (int mt = 0; mt < 4; mt++)
#pragma unroll
      for (int nt = 0; nt < 4; nt++)
        acc[mt][nt] = __builtin_amdgcn_mfma_f32_16x16x32_bf16(
            af[mt], bf[nt], acc[mt][nt], 0, 0, 0);
    __syncthreads();
  }

#pragma unroll
  for (int nt = 0; nt < 4; nt++) {
    int gn = n0 + wn * 64 + nt * 16 + cc;
#pragma unroll
    for (int mt = 0; mt < 4; mt++) {
      int gm = m0 + wm * 64 + mt * 16 + quad * 4;
#pragma unroll
      for (int r = 0; r < 4; r++)
        F[(size_t)(gm + r) * H0Q + gn] = acc[mt][nt][r];
    }
  }
}

// ---------------------------------------------------------------------------
// build_h0: block = 64 queries (256 blocks).
// Phase 1a: 4-way-parallel kNN scan (4 threads/query, 32 pts each).
// Phase 1b: t<64 merge 12 candidates (qt-major order == serial tie order).
// Phase 1c: t<192 pos embed, one (query, neighbor) pair per thread.
// Phase 2: G = pos.W0pos^T via MFMA with SWAPPED operands, fused F gather,
//          scale/bias/relu, H0 row = j*16384 + query (plane-major, no pads).
__global__ __launch_bounds__(256, 2) void build_h0(
    const float* __restrict__ xyz1, const float* __restrict__ xyz2,
    const float* __restrict__ lrf2, const float* __restrict__ w_pos,
    const float* __restrict__ pscale, const float* __restrict__ pbias,
    const u16* __restrict__ w0p, const float* __restrict__ F,
    const float* __restrict__ s0, const float* __restrict__ b0,
    u16* __restrict__ H0) {
  __shared__ float xyz2s[N2Q * 3];
  __shared__ float n2s[N2Q];
  __shared__ float lrfs[N2Q * 9];
  __shared__ float wps[DPOS * 4];
  __shared__ float pss[DPOS];
  __shared__ float pbs[DPOS];
  __shared__ int idxb[192];
  __shared__ float candd[64 * 13];  // stride 13: conflict-free merge reads
  __shared__ int candi[64 * 13];
  __shared__ alignas(16) u16 posb[12 * 512];  // 12 groups x (16 rows x 32)

  const int t = threadIdx.x;
  const int qb = blockIdx.x * 64;
  const int b = qb >> 11;

  for (int i = t; i < N2Q * 3; i += 256) xyz2s[i] = xyz2[b * N2Q * 3 + i];
  for (int i = t; i < N2Q * 9; i += 256) lrfs[i] = lrf2[b * N2Q * 9 + i];
  if (t < DPOS * 4) wps[t] = w_pos[t];
  if (t < DPOS) { pss[t] = pscale[t]; pbs[t] = pbias[t]; }
  __syncthreads();
  if (t < N2Q) {
    float x = xyz2s[t * 3], y = xyz2s[t * 3 + 1], z = xyz2s[t * 3 + 2];
    n2s[t] = x * x + y * y + z * z;
  }
  __syncthreads();

  // ---- phase 1a: partial kNN, 4 threads per query ----
  {
    const int ql = t >> 2, qt = t & 3;
    const int q = qb + ql;
    const float px = xyz1[q * 3], py = xyz1[q * 3 + 1], pz = xyz1[q * 3 + 2];
    const float pn = px * px + py * py + pz * pz;
    float d0 = 1e30f, d1 = 1e30f, d2v = 1e30f;
    int i0 = 0, i1 = 0, i2 = 0;
    const int ibeg = qt * 32;
    for (int i = ibeg; i < ibeg + 32; i++) {
      float dt = px * xyz2s[i * 3] + py * xyz2s[i * 3 + 1] + pz * xyz2s[i * 3 + 2];
      float d = pn + n2s[i] - 2.f * dt;
      if (d < d0) {
        d2v = d1; i2 = i1; d1 = d0; i1 = i0; d0 = d; i0 = i;
      } else if (d < d1) {
        d2v = d1; i2 = i1; d1 = d; i1 = i;
      } else if (d < d2v) {
        d2v = d; i2 = i;
      }
    }
    int base = ql * 13 + qt * 3;
    candd[base] = d0;      candi[base] = i0;
    candd[base + 1] = d1;  candi[base + 1] = i1;
    candd[base + 2] = d2v; candi[base + 2] = i2;
  }
  __syncthreads();

  // ---- phase 1b: merge 12 candidates per query (t<64) ----
  if (t < 64) {
    float d0 = 1e30f, d1 = 1e30f, d2v = 1e30f;
    int i0 = 0, i1 = 0, i2 = 0;
    int base = t * 13;
#pragma unroll
    for (int c = 0; c < 12; c++) {
      float d = candd[base + c];
      int id = candi[base + c];
      if (d < d0) {
        d2v = d1; i2 = i1; d1 = d0; i1 = i0; d0 = d; i0 = id;
      } else if (d < d1) {
        d2v = d1; i2 = i1; d1 = d; i1 = id;
      } else if (d < d2v) {
        d2v = d; i2 = id;
      }
    }
    idxb[t] = i0;
    idxb[64 + t] = i1;
    idxb[128 + t] = i2;
  }
  __syncthreads();

  // ---- phase 1c: pos embed, one (query, neighbor) per thread (t<192) ----
  if (t < 192) {
    const int ql = t & 63;
    const int q = qb + ql;
    const float px = xyz1[q * 3], py = xyz1[q * 3 + 1], pz = xyz1[q * 3 + 2];
    const int id = idxb[t];
    float rx = px - xyz2s[id * 3];
    float ry = py - xyz2s[id * 3 + 1];
    float rz = pz - xyz2s[id * 3 + 2];
    float rn = sqrtf(rx * rx + ry * ry + rz * rz);
    float inv = 1.f / fmaxf(rn, 1e-12f);
    float ux = rx * inv, uy = ry * inv, uz = rz * inv;
    const float* L = lrfs + id * 9;
    float a0 = L[0] * ux + L[1] * uy + L[2] * uz;
    float a1 = L[3] * ux + L[4] * uy + L[5] * uz;
    float a2 = L[6] * ux + L[7] * uy + L[8] * uz;
    u16* pd = posb + (t >> 4) * 512 + (t & 15) * 8;
#pragma unroll
    for (int o = 0; o < DPOS; o++) {
      float v = wps[o * 4] * rn + wps[o * 4 + 1] * a0 + wps[o * 4 + 2] * a1 +
                wps[o * 4 + 3] * a2;
      v = v * pss[o] + pbs[o];
      v = (v >= 0.f) ? v : 0.2f * v;  // LeakyReLU(0.2)
      pd[(o >> 3) * 128 + (o & 7)] = f2bf(v);
    }
  }
  __syncthreads();

  // ---- phase 2: H0 = relu((F[idx] + pos.W0pos^T)*s0 + b0) ----
  const int wv = t >> 6, lane = t & 63;
  const int quad = lane >> 4, cc = lane & 15;
  const float* Fr[3];
  u16* Hr[3];
#pragma unroll
  for (int mt = 0; mt < 3; mt++) {
    int rl = wv * 48 + mt * 16 + cc;  // wave's rows: groups 3*wv+mt
    Fr[mt] = F + ((size_t)(b * N2Q + idxb[rl])) * H0Q;
    int jj = rl >> 6, ql = rl & 63;
    Hr[mt] = H0 + ((size_t)(jj * NQ) + qb + ql) * H0Q;
  }
  bf16x8 afr[3];
#pragma unroll
  for (int mt = 0; mt < 3; mt++)
    afr[mt] = *(const bf16x8*)((const char*)posb + (wv * 3 + mt) * 1024 + (lane << 4));
  const f32x4 zf = {};
  for (int n0 = 0; n0 < H0Q; n0 += 128) {
    bf16x8 bfr[8];
#pragma unroll
    for (int nt = 0; nt < 8; nt++)
      bfr[nt] = *(const bf16x8*)(w0p + (n0 + nt * 16 + cc) * 32 + quad * 8);
    f32x4 acc[3][8];
#pragma unroll
    for (int mt = 0; mt < 3; mt++)
#pragma unroll
      for (int nt = 0; nt < 8; nt++)  // swapped operands: C row=h, col=query
        acc[mt][nt] = __builtin_amdgcn_mfma_f32_16x16x32_bf16(bfr[nt], afr[mt],
                                                              zf, 0, 0, 0);
#pragma unroll
    for (int nt = 0; nt < 8; nt++) {
      int hb = n0 + nt * 16 + quad * 4;
      f32x4 sv = *(const f32x4*)(s0 + hb);
      f32x4 bvv = *(const f32x4*)(b0 + hb);
#pragma unroll
      for (int mt = 0; mt < 3; mt++) {
        f32x4 fv = *(const f32x4*)(Fr[mt] + hb);
        u16x4 o4;
#pragma unroll
        for (int r = 0; r < 4; r++) {
          float h = (fv[r] + acc[mt][nt][r]) * sv[r] + bvv[r];
          h = h > 0.f ? h : 0.f;
          o4[r] = f2bf(h);
        }
        *(u16x4*)(Hr[mt] + hb) = o4;
      }
    }
  }
}

// ---------------------------------------------------------------------------
// gemm2: out[b][n][n1] = sum_j relu((H0_j[q][:] . W1[n][:])*s1[n] + b1[n]).
// M=16384 N=1024, K=512 x 3 planes flattened to 48 pipelined K-steps.
// 2-phase: double-buffered LDS; stage K-step s+1 BEFORE computing step s;
// single __syncthreads per step (its vmcnt(0) waits on loads issued a full
// compute-phase earlier). relu-fold into sum regs at plane boundaries.
__global__ __launch_bounds__(256, 2) void gemm2(const u16* __restrict__ A,
                                                const u16* __restrict__ W,
                                                const float* __restrict__ s,
                                                const float* __restrict__ bz,
                                                float* __restrict__ out) {
  __shared__ alignas(16) u16 As[2][128 * 32];
  __shared__ alignas(16) u16 Bs[2][128 * 32];
  const int id = blockIdx.x;            // 1024 blocks
  const int xcd = id & 7, g = id >> 3;  // g 0..127
  const int m0 = (xcd * 16 + (g >> 3)) * 128;  // 16 m-tiles per XCD
  const int n0 = (g & 7) * 128;
  const int t = threadIdx.x;
  const int wv = t >> 6, lane = t & 63;
  const int wm = wv >> 1, wn = wv & 1;
  const int quad = lane >> 4, cc = lane & 15;
  const int srow = lane & 15, skc = quad * 8;

  float sv[4], bv[4];
#pragma unroll
  for (int nt = 0; nt < 4; nt++) {
    int gn = n0 + wn * 64 + nt * 16 + cc;
    sv[nt] = s[gn];
    bv[nt] = bz[gn];
  }

  // per-thread staging source offsets (elements) and LDS dst
  const size_t aOff0 = (size_t)(m0 + wv * 16 + srow) * 512 + skc;
  const size_t aOff1 = aOff0 + (size_t)64 * 512;
  const size_t wOff0 = (size_t)(n0 + wv * 16 + srow) * 512 + skc;
  const size_t wOff1 = wOff0 + (size_t)64 * 512;
  const int ldst = wv * 1024 + (lane << 4);

  auto stage = [&](int sIdx, int buf) {
    const u16* Aj = A + (size_t)(sIdx >> 4) * ((size_t)NQ * H0Q);
    const int k0 = (sIdx & 15) << 5;
    char* dA = (char*)As[buf] + ldst;
    char* dB = (char*)Bs[buf] + ldst;
    load16_lds(Aj + aOff0 + k0, dA);
    load16_lds(Aj + aOff1 + k0, dA + 4096);
    load16_lds(W + wOff0 + k0, dB);
    load16_lds(W + wOff1 + k0, dB + 4096);
  };

  f32x4 sum[4][4] = {};
  f32x4 acc[4][4] = {};

  stage(0, 0);
  __syncthreads();

#pragma unroll 2
  for (int sI = 0; sI < 48; sI++) {
    const int cur = sI & 1;
    if (sI < 47) stage(sI + 1, cur ^ 1);  // prefetch overlaps compute below
    bf16x8 af[4], bf[4];
#pragma unroll
    for (int mt = 0; mt < 4; mt++)
      af[mt] = *(const bf16x8*)((const char*)As[cur] + (wm * 4 + mt) * 1024 +
                                (lane << 4));
#pragma unroll
    for (int nt = 0; nt < 4; nt++)
      bf[nt] = *(const bf16x8*)((const char*)Bs[cur] + (wn * 4 + nt) * 1024 +
                                (lane << 4));
#pragma unroll
    for (int mt = 0; mt < 4; mt++)
#pragma unroll
      for (int nt = 0; nt < 4; nt++)
        acc[mt][nt] = __builtin_amdgcn_mfma_f32_16x16x32_bf16(
            af[mt], bf[nt], acc[mt][nt], 0, 0, 0);
    if ((sI & 15) == 15) {  // plane boundary: relu-fold, register-only
#pragma unroll
      for (int mt = 0; mt < 4; mt++)
#pragma unroll
        for (int nt = 0; nt < 4; nt++) {
#pragma unroll
          for (int r = 0; r < 4; r++) {
            float h = acc[mt][nt][r] * sv[nt] + bv[nt];
            sum[mt][nt][r] += (h > 0.f ? h : 0.f);
          }
          acc[mt][nt] = f32x4{};
        }
    }
    __syncthreads();  // vmcnt(0)+barrier: prefetch has had a phase to land
  }

#pragma unroll
  for (int nt = 0; nt < 4; nt++) {
    int gn = n0 + wn * 64 + nt * 16 + cc;
#pragma unroll
    for (int mt = 0; mt < 4; mt++) {
      int gm = m0 + wm * 64 + mt * 16 + quad * 4;
#pragma unroll
      for (int r = 0; r < 4; r++) {
        int q = gm + r;
        out[((size_t)(q >> 11) * H1Q + gn) * N1Q + (q & 2047)] = sum[mt][nt][r];
      }
    }
  }
}

// ---------------------------------------------------------------------------
extern "C" void kernel_launch(void* const* d_in, const int* in_sizes, int n_in,
                              void* d_out, int out_size, void* d_ws,
                              size_t ws_size, hipStream_t stream) {
  const float* xyz1 = (const float*)d_in[0];
  const float* xyz2 = (const float*)d_in[1];
  const float* feat2 = (const float*)d_in[2];
  const float* lrf2 = (const float*)d_in[3];
  const float* w_pos = (const float*)d_in[4];
  const float* pscale = (const float*)d_in[5];
  const float* pbias = (const float*)d_in[6];
  const float* w0 = (const float*)d_in[7];
  const float* s0 = (const float*)d_in[8];
  const float* b0 = (const float*)d_in[9];
  const float* w1 = (const float*)d_in[10];
  const float* s1 = (const float*)d_in[11];
  const float* b1 = (const float*)d_in[12];
  float* out = (float*)d_out;

  char* ws = (char*)d_ws;
  u16* w0f = (u16*)(ws + WS_W0F);
  u16* w0p = (u16*)(ws + WS_W0P);
  u16* w1b = (u16*)(ws + WS_W1);
  u16* f2b = (u16*)(ws + WS_F2B);
  float* F = (float*)(ws + WS_F);
  u16* H0 = (u16*)(ws + WS_H0);

  convert_inputs<<<933888 / 256, 256, 0, stream>>>(w0, w1, feat2, w0f, w0p,
                                                   w1b, f2b);
  fgemm<<<32, 256, 0, stream>>>(f2b, w0f, F);
  build_h0<<<NQ / 64, 256, 0, stream>>>(xyz1, xyz2, lrf2, w_pos, pscale,
                                        pbias, w0p, F, s0, b0, H0);
  gemm2<<<1024, 256, 0, stream>>>(H0, w1b, s1, b1, out);
}

// Round 3
// 242.071 us; speedup vs baseline: 1.1029x; 1.0478x over previous
//
#include <hip/hip_runtime.h>

// ---------------------------------------------------------------------------
// PointTransformerForSegmentation, round 8:
//   convert   : bf16-cast w0feat / w0pos / w1 / feat2
//   fgemm     : F[b*128+n2][512] = feat2 . W0feat^T   (f32, tiny GEMM)
//   build_h0  : kNN (4-way parallel scan + merge) + pos embed (192 thr) +
//               K=32 MFMA pos.W0pos^T + F gather -> H0 plane-major bf16
//   gemm2     : 512-thread 128x128 tile, TRIPLE-buffered LDS, counted
//               s_waitcnt vmcnt(4) + raw s_barriers (loads stay in flight
//               across barriers, T3+T4), setprio around MFMA cluster (T5).
//               3 j-planes flattened to 48 K-steps, relu-fold at boundaries.
// LDS layout for all GEMMs: fragment-linear 16-row groups (chunk-major),
// lane l reads group*1024 + l*16 -> sequential banks, zero conflicts.
// ---------------------------------------------------------------------------

typedef unsigned short u16;
typedef __bf16 bf16x8 __attribute__((ext_vector_type(8)));
typedef float f32x4 __attribute__((ext_vector_type(4)));
typedef u16 u16x4 __attribute__((ext_vector_type(4)));

#define BQ 8
#define N1Q 2048
#define N2Q 128
#define C2Q 256
#define DPOS 32
#define H0Q 512
#define H1Q 1024
#define NQ (BQ * N1Q)   // 16384 queries

// workspace layout (bytes)
#define WS_W0F 0u          // 512*256*2   = 262144
#define WS_W0P 262144u     // 512*32*2    = 32768
#define WS_W1 294912u      // 1024*512*2  = 1048576
#define WS_F2B 1343488u    // 1024*256*2  = 524288
#define WS_F 1867776u      // 1024*512*4  = 2097152
#define WS_H0 3964928u     // 3*16384*512*2 = 50331648 (end 54296576)

__device__ __forceinline__ u16 f2bf(float f) {
  unsigned int u = __builtin_bit_cast(unsigned int, f);
  return (u16)((u + 0x7FFFu + ((u >> 16) & 1u)) >> 16);
}

__device__ __forceinline__ void load16_lds(const void* g, void* l) {
  __builtin_amdgcn_global_load_lds(
      (const __attribute__((address_space(1))) unsigned int*)g,
      (__attribute__((address_space(3))) unsigned int*)l, 16, 0, 0);
}

// ---------------------------------------------------------------------------
// convert: w0feat (512x256), w0pos (512x32), w1 (1024x512), feat2 (1024x256)
__global__ void convert_inputs(const float* __restrict__ w0,
                               const float* __restrict__ w1,
                               const float* __restrict__ feat2,
                               u16* __restrict__ w0f, u16* __restrict__ w0p,
                               u16* __restrict__ w1b, u16* __restrict__ f2b) {
  int i = blockIdx.x * 256 + threadIdx.x;  // grid covers 933888 exactly
  if (i < 131072) {
    int h = i >> 8, c = i & 255;
    w0f[i] = f2bf(w0[h * 288 + c]);
  } else if (i < 147456) {
    int j = i - 131072;
    int h = j >> 5, c = j & 31;
    w0p[j] = f2bf(w0[h * 288 + 256 + c]);
  } else if (i < 671744) {
    int j = i - 147456;
    w1b[j] = f2bf(w1[j]);
  } else {
    int j = i - 671744;  // < 262144
    f2b[j] = f2bf(feat2[j]);
  }
}

// ---------------------------------------------------------------------------
// fgemm: F[m][n] = sum_k feat2bf[m][k]*w0featbf[n][k], f32 out.
// M=1024 N=512 K=256, 128x128 tile, 32 blocks.
__global__ __launch_bounds__(256, 2) void fgemm(const u16* __restrict__ A,
                                                const u16* __restrict__ W,
                                                float* __restrict__ F) {
  __shared__ alignas(16) u16 As[128 * 32];
  __shared__ alignas(16) u16 Bs[128 * 32];
  const int m0 = (blockIdx.x >> 2) * 128, n0 = (blockIdx.x & 3) * 128;
  const int t = threadIdx.x;
  const int wv = t >> 6, lane = t & 63;
  const int wm = wv >> 1, wn = wv & 1;
  const int quad = lane >> 4, cc = lane & 15;
  const int srow = lane & 15, skc = quad * 8;
  f32x4 acc[4][4] = {};

  for (int k0 = 0; k0 < 256; k0 += 32) {
#pragma unroll
    for (int i = 0; i < 2; i++) {
      int g = i * 4 + wv;
      load16_lds(A + (size_t)(m0 + g * 16 + srow) * 256 + k0 + skc,
                 (char*)As + g * 1024 + (lane << 4));
      load16_lds(W + (size_t)(n0 + g * 16 + srow) * 256 + k0 + skc,
                 (char*)Bs + g * 1024 + (lane << 4));
    }
    __syncthreads();
    bf16x8 af[4], bf[4];
#pragma unroll
    for (int mt = 0; mt < 4; mt++)
      af[mt] = *(const bf16x8*)((const char*)As + (wm * 4 + mt) * 1024 + (lane << 4));
#pragma unroll
    for (int nt = 0; nt < 4; nt++)
      bf[nt] = *(const bf16x8*)((const char*)Bs + (wn * 4 + nt) * 1024 + (lane << 4));
#pragma unroll
    for (int mt = 0; mt < 4; mt++)
#pragma unroll
      for (int nt = 0; nt < 4; nt++)
        acc[mt][nt] = __builtin_amdgcn_mfma_f32_16x16x32_bf16(
            af[mt], bf[nt], acc[mt][nt], 0, 0, 0);
    __syncthreads();
  }

#pragma unroll
  for (int nt = 0; nt < 4; nt++) {
    int gn = n0 + wn * 64 + nt * 16 + cc;
#pragma unroll
    for (int mt = 0; mt < 4; mt++) {
      int gm = m0 + wm * 64 + mt * 16 + quad * 4;
#pragma unroll
      for (int r = 0; r < 4; r++)
        F[(size_t)(gm + r) * H0Q + gn] = acc[mt][nt][r];
    }
  }
}

// ---------------------------------------------------------------------------
// build_h0: block = 64 queries (256 blocks).
// Phase 1a: 4-way-parallel kNN scan (4 threads/query, 32 pts each).
// Phase 1b: t<64 merge 12 candidates (qt-major order == serial tie order).
// Phase 1c: t<192 pos embed, one (query, neighbor) pair per thread.
// Phase 2: G = pos.W0pos^T via MFMA with SWAPPED operands, fused F gather,
//          scale/bias/relu, H0 row = j*16384 + query (plane-major, no pads).
__global__ __launch_bounds__(256, 2) void build_h0(
    const float* __restrict__ xyz1, const float* __restrict__ xyz2,
    const float* __restrict__ lrf2, const float* __restrict__ w_pos,
    const float* __restrict__ pscale, const float* __restrict__ pbias,
    const u16* __restrict__ w0p, const float* __restrict__ F,
    const float* __restrict__ s0, const float* __restrict__ b0,
    u16* __restrict__ H0) {
  __shared__ float xyz2s[N2Q * 3];
  __shared__ float n2s[N2Q];
  __shared__ float lrfs[N2Q * 9];
  __shared__ float wps[DPOS * 4];
  __shared__ float pss[DPOS];
  __shared__ float pbs[DPOS];
  __shared__ int idxb[192];
  __shared__ float candd[64 * 13];  // stride 13: conflict-free merge reads
  __shared__ int candi[64 * 13];
  __shared__ alignas(16) u16 posb[12 * 512];  // 12 groups x (16 rows x 32)

  const int t = threadIdx.x;
  const int qb = blockIdx.x * 64;
  const int b = qb >> 11;

  for (int i = t; i < N2Q * 3; i += 256) xyz2s[i] = xyz2[b * N2Q * 3 + i];
  for (int i = t; i < N2Q * 9; i += 256) lrfs[i] = lrf2[b * N2Q * 9 + i];
  if (t < DPOS * 4) wps[t] = w_pos[t];
  if (t < DPOS) { pss[t] = pscale[t]; pbs[t] = pbias[t]; }
  __syncthreads();
  if (t < N2Q) {
    float x = xyz2s[t * 3], y = xyz2s[t * 3 + 1], z = xyz2s[t * 3 + 2];
    n2s[t] = x * x + y * y + z * z;
  }
  __syncthreads();

  // ---- phase 1a: partial kNN, 4 threads per query ----
  {
    const int ql = t >> 2, qt = t & 3;
    const int q = qb + ql;
    const float px = xyz1[q * 3], py = xyz1[q * 3 + 1], pz = xyz1[q * 3 + 2];
    const float pn = px * px + py * py + pz * pz;
    float d0 = 1e30f, d1 = 1e30f, d2v = 1e30f;
    int i0 = 0, i1 = 0, i2 = 0;
    const int ibeg = qt * 32;
    for (int i = ibeg; i < ibeg + 32; i++) {
      float dt = px * xyz2s[i * 3] + py * xyz2s[i * 3 + 1] + pz * xyz2s[i * 3 + 2];
      float d = pn + n2s[i] - 2.f * dt;
      if (d < d0) {
        d2v = d1; i2 = i1; d1 = d0; i1 = i0; d0 = d; i0 = i;
      } else if (d < d1) {
        d2v = d1; i2 = i1; d1 = d; i1 = i;
      } else if (d < d2v) {
        d2v = d; i2 = i;
      }
    }
    int base = ql * 13 + qt * 3;
    candd[base] = d0;      candi[base] = i0;
    candd[base + 1] = d1;  candi[base + 1] = i1;
    candd[base + 2] = d2v; candi[base + 2] = i2;
  }
  __syncthreads();

  // ---- phase 1b: merge 12 candidates per query (t<64) ----
  if (t < 64) {
    float d0 = 1e30f, d1 = 1e30f, d2v = 1e30f;
    int i0 = 0, i1 = 0, i2 = 0;
    int base = t * 13;
#pragma unroll
    for (int c = 0; c < 12; c++) {
      float d = candd[base + c];
      int id = candi[base + c];
      if (d < d0) {
        d2v = d1; i2 = i1; d1 = d0; i1 = i0; d0 = d; i0 = id;
      } else if (d < d1) {
        d2v = d1; i2 = i1; d1 = d; i1 = id;
      } else if (d < d2v) {
        d2v = d; i2 = id;
      }
    }
    idxb[t] = i0;
    idxb[64 + t] = i1;
    idxb[128 + t] = i2;
  }
  __syncthreads();

  // ---- phase 1c: pos embed, one (query, neighbor) per thread (t<192) ----
  if (t < 192) {
    const int ql = t & 63;
    const int q = qb + ql;
    const float px = xyz1[q * 3], py = xyz1[q * 3 + 1], pz = xyz1[q * 3 + 2];
    const int id = idxb[t];
    float rx = px - xyz2s[id * 3];
    float ry = py - xyz2s[id * 3 + 1];
    float rz = pz - xyz2s[id * 3 + 2];
    float rn = sqrtf(rx * rx + ry * ry + rz * rz);
    float inv = 1.f / fmaxf(rn, 1e-12f);
    float ux = rx * inv, uy = ry * inv, uz = rz * inv;
    const float* L = lrfs + id * 9;
    float a0 = L[0] * ux + L[1] * uy + L[2] * uz;
    float a1 = L[3] * ux + L[4] * uy + L[5] * uz;
    float a2 = L[6] * ux + L[7] * uy + L[8] * uz;
    u16* pd = posb + (t >> 4) * 512 + (t & 15) * 8;
#pragma unroll
    for (int o = 0; o < DPOS; o++) {
      float v = wps[o * 4] * rn + wps[o * 4 + 1] * a0 + wps[o * 4 + 2] * a1 +
                wps[o * 4 + 3] * a2;
      v = v * pss[o] + pbs[o];
      v = (v >= 0.f) ? v : 0.2f * v;  // LeakyReLU(0.2)
      pd[(o >> 3) * 128 + (o & 7)] = f2bf(v);
    }
  }
  __syncthreads();

  // ---- phase 2: H0 = relu((F[idx] + pos.W0pos^T)*s0 + b0) ----
  const int wv = t >> 6, lane = t & 63;
  const int quad = lane >> 4, cc = lane & 15;
  const float* Fr[3];
  u16* Hr[3];
#pragma unroll
  for (int mt = 0; mt < 3; mt++) {
    int rl = wv * 48 + mt * 16 + cc;  // wave's rows: groups 3*wv+mt
    Fr[mt] = F + ((size_t)(b * N2Q + idxb[rl])) * H0Q;
    int jj = rl >> 6, ql = rl & 63;
    Hr[mt] = H0 + ((size_t)(jj * NQ) + qb + ql) * H0Q;
  }
  bf16x8 afr[3];
#pragma unroll
  for (int mt = 0; mt < 3; mt++)
    afr[mt] = *(const bf16x8*)((const char*)posb + (wv * 3 + mt) * 1024 + (lane << 4));
  const f32x4 zf = {};
  for (int n0 = 0; n0 < H0Q; n0 += 128) {
    bf16x8 bfr[8];
#pragma unroll
    for (int nt = 0; nt < 8; nt++)
      bfr[nt] = *(const bf16x8*)(w0p + (n0 + nt * 16 + cc) * 32 + quad * 8);
    f32x4 acc[3][8];
#pragma unroll
    for (int mt = 0; mt < 3; mt++)
#pragma unroll
      for (int nt = 0; nt < 8; nt++)  // swapped operands: C row=h, col=query
        acc[mt][nt] = __builtin_amdgcn_mfma_f32_16x16x32_bf16(bfr[nt], afr[mt],
                                                              zf, 0, 0, 0);
#pragma unroll
    for (int nt = 0; nt < 8; nt++) {
      int hb = n0 + nt * 16 + quad * 4;
      f32x4 sv = *(const f32x4*)(s0 + hb);
      f32x4 bvv = *(const f32x4*)(b0 + hb);
#pragma unroll
      for (int mt = 0; mt < 3; mt++) {
        f32x4 fv = *(const f32x4*)(Fr[mt] + hb);
        u16x4 o4;
#pragma unroll
        for (int r = 0; r < 4; r++) {
          float h = (fv[r] + acc[mt][nt][r]) * sv[r] + bvv[r];
          h = h > 0.f ? h : 0.f;
          o4[r] = f2bf(h);
        }
        *(u16x4*)(Hr[mt] + hb) = o4;
      }
    }
  }
}

// ---------------------------------------------------------------------------
// gemm2: out[b][n][n1] = sum_j relu((H0_j[q][:] . W1[n][:])*s1[n] + b1[n]).
// M=16384 N=1024, K=512 x 3 planes flattened to 48 K-steps of BK=32.
// 512 threads (8 waves, 2M x 4N). TRIPLE-buffered LDS; per step:
//   s_waitcnt vmcnt(4)   (stage sI landed; stages sI+1,sI+2 stay in flight)
//   s_barrier            (all waves see the data)
//   ds_read frags; s_waitcnt lgkmcnt(0)
//   s_barrier            (all waves done reading buf bi)
//   stage(sI+3 -> bi)    (overwrite is now safe; 2 loads/thread)
//   setprio(1); 8 MFMA; setprio(0); plane-boundary relu-fold
// vmcnt retires in-order, so the tail (fewer stages in flight) is safe.
__global__ __launch_bounds__(512, 2) void gemm2(const u16* __restrict__ A,
                                                const u16* __restrict__ W,
                                                const float* __restrict__ s,
                                                const float* __restrict__ bz,
                                                float* __restrict__ out) {
  __shared__ alignas(16) u16 As[3][128 * 32];
  __shared__ alignas(16) u16 Bs[3][128 * 32];
  const int id = blockIdx.x;            // 1024 blocks
  const int xcd = id & 7, g = id >> 3;  // g 0..127
  const int m0 = (xcd * 16 + (g >> 3)) * 128;  // 16 m-tiles per XCD
  const int n0 = (g & 7) * 128;
  const int t = threadIdx.x;
  const int wv = t >> 6, lane = t & 63;
  const int wm = wv >> 2, wn = wv & 3;  // 2 x 4 wave grid
  const int quad = lane >> 4, cc = lane & 15;

  // staging: wave wv owns 16-row group wv of each tile; 2 loads/thread.
  const int srow = lane & 15, skc = quad * 8;
  const size_t aOff = (size_t)(m0 + wv * 16 + srow) * 512 + skc;
  const size_t wOff = (size_t)(n0 + wv * 16 + srow) * 512 + skc;
  const int ldst = wv * 1024 + (lane << 4);

  float sv[2], bv[2];
#pragma unroll
  for (int nt = 0; nt < 2; nt++) {
    int gn = n0 + wn * 32 + nt * 16 + cc;
    sv[nt] = s[gn];
    bv[nt] = bz[gn];
  }

  auto stage = [&](int sIdx, int buf) {
    const u16* Aj = A + (size_t)(sIdx >> 4) * ((size_t)NQ * H0Q);
    const int k0 = (sIdx & 15) << 5;
    load16_lds(Aj + aOff + k0, (char*)As[buf] + ldst);
    load16_lds(W + wOff + (size_t)k0, (char*)Bs[buf] + ldst);
  };

  f32x4 sum[4][2] = {};
  f32x4 acc[4][2] = {};

  stage(0, 0);
  stage(1, 1);
  stage(2, 2);

#pragma unroll 3
  for (int sI = 0; sI < 48; sI++) {
    const int bi = sI % 3;
    asm volatile("s_waitcnt vmcnt(4)" ::: "memory");
    __builtin_amdgcn_s_barrier();
    bf16x8 af[4], bf[2];
#pragma unroll
    for (int mt = 0; mt < 4; mt++)
      af[mt] = *(const bf16x8*)((const char*)As[bi] + (wm * 4 + mt) * 1024 +
                                (lane << 4));
#pragma unroll
    for (int nt = 0; nt < 2; nt++)
      bf[nt] = *(const bf16x8*)((const char*)Bs[bi] + (wn * 2 + nt) * 1024 +
                                (lane << 4));
    asm volatile("s_waitcnt lgkmcnt(0)" ::: "memory");
    __builtin_amdgcn_s_barrier();
    if (sI + 3 < 48) stage(sI + 3, bi);
    __builtin_amdgcn_s_setprio(1);
#pragma unroll
    for (int mt = 0; mt < 4; mt++)
#pragma unroll
      for (int nt = 0; nt < 2; nt++)
        acc[mt][nt] = __builtin_amdgcn_mfma_f32_16x16x32_bf16(
            af[mt], bf[nt], acc[mt][nt], 0, 0, 0);
    __builtin_amdgcn_s_setprio(0);
    if ((sI & 15) == 15) {  // plane boundary: relu-fold, register-only
#pragma unroll
      for (int mt = 0; mt < 4; mt++)
#pragma unroll
        for (int nt = 0; nt < 2; nt++) {
#pragma unroll
          for (int r = 0; r < 4; r++) {
            float h = acc[mt][nt][r] * sv[nt] + bv[nt];
            sum[mt][nt][r] += (h > 0.f ? h : 0.f);
          }
          acc[mt][nt] = f32x4{};
        }
    }
  }

#pragma unroll
  for (int nt = 0; nt < 2; nt++) {
    int gn = n0 + wn * 32 + nt * 16 + cc;
#pragma unroll
    for (int mt = 0; mt < 4; mt++) {
      int gm = m0 + wm * 64 + mt * 16 + quad * 4;
#pragma unroll
      for (int r = 0; r < 4; r++) {
        int q = gm + r;
        out[((size_t)(q >> 11) * H1Q + gn) * N1Q + (q & 2047)] = sum[mt][nt][r];
      }
    }
  }
}

// ---------------------------------------------------------------------------
extern "C" void kernel_launch(void* const* d_in, const int* in_sizes, int n_in,
                              void* d_out, int out_size, void* d_ws,
                              size_t ws_size, hipStream_t stream) {
  const float* xyz1 = (const float*)d_in[0];
  const float* xyz2 = (const float*)d_in[1];
  const float* feat2 = (const float*)d_in[2];
  const float* lrf2 = (const float*)d_in[3];
  const float* w_pos = (const float*)d_in[4];
  const float* pscale = (const float*)d_in[5];
  const float* pbias = (const float*)d_in[6];
  const float* w0 = (const float*)d_in[7];
  const float* s0 = (const float*)d_in[8];
  const float* b0 = (const float*)d_in[9];
  const float* w1 = (const float*)d_in[10];
  const float* s1 = (const float*)d_in[11];
  const float* b1 = (const float*)d_in[12];
  float* out = (float*)d_out;

  char* ws = (char*)d_ws;
  u16* w0f = (u16*)(ws + WS_W0F);
  u16* w0p = (u16*)(ws + WS_W0P);
  u16* w1b = (u16*)(ws + WS_W1);
  u16* f2b = (u16*)(ws + WS_F2B);
  float* F = (float*)(ws + WS_F);
  u16* H0 = (u16*)(ws + WS_H0);

  convert_inputs<<<933888 / 256, 256, 0, stream>>>(w0, w1, feat2, w0f, w0p,
                                                   w1b, f2b);
  fgemm<<<32, 256, 0, stream>>>(f2b, w0f, F);
  build_h0<<<NQ / 64, 256, 0, stream>>>(xyz1, xyz2, lrf2, w_pos, pscale,
                                        pbias, w0p, F, s0, b0, H0);
  gemm2<<<1024, 512, 0, stream>>>(H0, w1b, s1, b1, out);
}

// Round 4
// 231.097 us; speedup vs baseline: 1.1553x; 1.0475x over previous
//
#include <hip/hip_runtime.h>

// ---------------------------------------------------------------------------
// PointTransformerForSegmentation, round 9:
//   convert   : bf16-cast w0feat / w0pos / w1 / feat2
//   fgemm     : F[b*128+n2][512] = feat2 . W0feat^T   (f32, tiny GEMM)
//   build_h0  : kNN (4-way parallel scan + merge) + pos embed (192 thr) +
//               K=32 MFMA pos.W0pos^T + F gather -> H0 plane-major bf16
//   gemm2     : BM=128 x BN=256, BK=64, 512 thr (8 waves 2Mx4N, 64x64/wave).
//               Triple-buffered K-tile LDS (144 KiB), counted vmcnt(12/6/0)
//               so 2 K-tiles of loads stay in flight across barriers.
//               32 MFMA per wave per barrier-pair (4x round 8).
//               3 j-planes flattened to 24 K-tiles, relu-fold at kt 7/15/23.
// LDS layout: fragment-linear 1KB groups (16 rows x 32 k), lane l reads/writes
// group*1024 + l*16 -> sequential banks, zero conflicts.
// ---------------------------------------------------------------------------

typedef unsigned short u16;
typedef __bf16 bf16x8 __attribute__((ext_vector_type(8)));
typedef float f32x4 __attribute__((ext_vector_type(4)));
typedef u16 u16x4 __attribute__((ext_vector_type(4)));

#define BQ 8
#define N1Q 2048
#define N2Q 128
#define C2Q 256
#define DPOS 32
#define H0Q 512
#define H1Q 1024
#define NQ (BQ * N1Q)   // 16384 queries

// workspace layout (bytes)
#define WS_W0F 0u          // 512*256*2   = 262144
#define WS_W0P 262144u     // 512*32*2    = 32768
#define WS_W1 294912u      // 1024*512*2  = 1048576
#define WS_F2B 1343488u    // 1024*256*2  = 524288
#define WS_F 1867776u      // 1024*512*4  = 2097152
#define WS_H0 3964928u     // 3*16384*512*2 = 50331648 (end 54296576)

__device__ __forceinline__ u16 f2bf(float f) {
  unsigned int u = __builtin_bit_cast(unsigned int, f);
  return (u16)((u + 0x7FFFu + ((u >> 16) & 1u)) >> 16);
}

__device__ __forceinline__ void load16_lds(const void* g, void* l) {
  __builtin_amdgcn_global_load_lds(
      (const __attribute__((address_space(1))) unsigned int*)g,
      (__attribute__((address_space(3))) unsigned int*)l, 16, 0, 0);
}

// ---------------------------------------------------------------------------
// convert: w0feat (512x256), w0pos (512x32), w1 (1024x512), feat2 (1024x256)
__global__ void convert_inputs(const float* __restrict__ w0,
                               const float* __restrict__ w1,
                               const float* __restrict__ feat2,
                               u16* __restrict__ w0f, u16* __restrict__ w0p,
                               u16* __restrict__ w1b, u16* __restrict__ f2b) {
  int i = blockIdx.x * 256 + threadIdx.x;  // grid covers 933888 exactly
  if (i < 131072) {
    int h = i >> 8, c = i & 255;
    w0f[i] = f2bf(w0[h * 288 + c]);
  } else if (i < 147456) {
    int j = i - 131072;
    int h = j >> 5, c = j & 31;
    w0p[j] = f2bf(w0[h * 288 + 256 + c]);
  } else if (i < 671744) {
    int j = i - 147456;
    w1b[j] = f2bf(w1[j]);
  } else {
    int j = i - 671744;  // < 262144
    f2b[j] = f2bf(feat2[j]);
  }
}

// ---------------------------------------------------------------------------
// fgemm: F[m][n] = sum_k feat2bf[m][k]*w0featbf[n][k], f32 out.
// M=1024 N=512 K=256, 128x128 tile, 32 blocks.
__global__ __launch_bounds__(256, 2) void fgemm(const u16* __restrict__ A,
                                                const u16* __restrict__ W,
                                                float* __restrict__ F) {
  __shared__ alignas(16) u16 As[128 * 32];
  __shared__ alignas(16) u16 Bs[128 * 32];
  const int m0 = (blockIdx.x >> 2) * 128, n0 = (blockIdx.x & 3) * 128;
  const int t = threadIdx.x;
  const int wv = t >> 6, lane = t & 63;
  const int wm = wv >> 1, wn = wv & 1;
  const int quad = lane >> 4, cc = lane & 15;
  const int srow = lane & 15, skc = quad * 8;
  f32x4 acc[4][4] = {};

  for (int k0 = 0; k0 < 256; k0 += 32) {
#pragma unroll
    for (int i = 0; i < 2; i++) {
      int g = i * 4 + wv;
      load16_lds(A + (size_t)(m0 + g * 16 + srow) * 256 + k0 + skc,
                 (char*)As + g * 1024 + (lane << 4));
      load16_lds(W + (size_t)(n0 + g * 16 + srow) * 256 + k0 + skc,
                 (char*)Bs + g * 1024 + (lane << 4));
    }
    __syncthreads();
    bf16x8 af[4], bf[4];
#pragma unroll
    for (int mt = 0; mt < 4; mt++)
      af[mt] = *(const bf16x8*)((const char*)As + (wm * 4 + mt) * 1024 + (lane << 4));
#pragma unroll
    for (int nt = 0; nt < 4; nt++)
      bf[nt] = *(const bf16x8*)((const char*)Bs + (wn * 4 + nt) * 1024 + (lane << 4));
#pragma unroll
    for (int mt = 0; mt < 4; mt++)
#pragma unroll
      for (int nt = 0; nt < 4; nt++)
        acc[mt][nt] = __builtin_amdgcn_mfma_f32_16x16x32_bf16(
            af[mt], bf[nt], acc[mt][nt], 0, 0, 0);
    __syncthreads();
  }

#pragma unroll
  for (int nt = 0; nt < 4; nt++) {
    int gn = n0 + wn * 64 + nt * 16 + cc;
#pragma unroll
    for (int mt = 0; mt < 4; mt++) {
      int gm = m0 + wm * 64 + mt * 16 + quad * 4;
#pragma unroll
      for (int r = 0; r < 4; r++)
        F[(size_t)(gm + r) * H0Q + gn] = acc[mt][nt][r];
    }
  }
}

// ---------------------------------------------------------------------------
// build_h0: block = 64 queries (256 blocks).
// Phase 1a: 4-way-parallel kNN scan (4 threads/query, 32 pts each).
// Phase 1b: t<64 merge 12 candidates (qt-major order == serial tie order).
// Phase 1c: t<192 pos embed, one (query, neighbor) pair per thread.
// Phase 2: G = pos.W0pos^T via MFMA with SWAPPED operands, fused F gather,
//          scale/bias/relu, H0 row = j*16384 + query (plane-major, no pads).
__global__ __launch_bounds__(256, 2) void build_h0(
    const float* __restrict__ xyz1, const float* __restrict__ xyz2,
    const float* __restrict__ lrf2, const float* __restrict__ w_pos,
    const float* __restrict__ pscale, const float* __restrict__ pbias,
    const u16* __restrict__ w0p, const float* __restrict__ F,
    const float* __restrict__ s0, const float* __restrict__ b0,
    u16* __restrict__ H0) {
  __shared__ float xyz2s[N2Q * 3];
  __shared__ float n2s[N2Q];
  __shared__ float lrfs[N2Q * 9];
  __shared__ float wps[DPOS * 4];
  __shared__ float pss[DPOS];
  __shared__ float pbs[DPOS];
  __shared__ int idxb[192];
  __shared__ float candd[64 * 13];  // stride 13: conflict-free merge reads
  __shared__ int candi[64 * 13];
  __shared__ alignas(16) u16 posb[12 * 512];  // 12 groups x (16 rows x 32)

  const int t = threadIdx.x;
  const int qb = blockIdx.x * 64;
  const int b = qb >> 11;

  for (int i = t; i < N2Q * 3; i += 256) xyz2s[i] = xyz2[b * N2Q * 3 + i];
  for (int i = t; i < N2Q * 9; i += 256) lrfs[i] = lrf2[b * N2Q * 9 + i];
  if (t < DPOS * 4) wps[t] = w_pos[t];
  if (t < DPOS) { pss[t] = pscale[t]; pbs[t] = pbias[t]; }
  __syncthreads();
  if (t < N2Q) {
    float x = xyz2s[t * 3], y = xyz2s[t * 3 + 1], z = xyz2s[t * 3 + 2];
    n2s[t] = x * x + y * y + z * z;
  }
  __syncthreads();

  // ---- phase 1a: partial kNN, 4 threads per query ----
  {
    const int ql = t >> 2, qt = t & 3;
    const int q = qb + ql;
    const float px = xyz1[q * 3], py = xyz1[q * 3 + 1], pz = xyz1[q * 3 + 2];
    const float pn = px * px + py * py + pz * pz;
    float d0 = 1e30f, d1 = 1e30f, d2v = 1e30f;
    int i0 = 0, i1 = 0, i2 = 0;
    const int ibeg = qt * 32;
    for (int i = ibeg; i < ibeg + 32; i++) {
      float dt = px * xyz2s[i * 3] + py * xyz2s[i * 3 + 1] + pz * xyz2s[i * 3 + 2];
      float d = pn + n2s[i] - 2.f * dt;
      if (d < d0) {
        d2v = d1; i2 = i1; d1 = d0; i1 = i0; d0 = d; i0 = i;
      } else if (d < d1) {
        d2v = d1; i2 = i1; d1 = d; i1 = i;
      } else if (d < d2v) {
        d2v = d; i2 = i;
      }
    }
    int base = ql * 13 + qt * 3;
    candd[base] = d0;      candi[base] = i0;
    candd[base + 1] = d1;  candi[base + 1] = i1;
    candd[base + 2] = d2v; candi[base + 2] = i2;
  }
  __syncthreads();

  // ---- phase 1b: merge 12 candidates per query (t<64) ----
  if (t < 64) {
    float d0 = 1e30f, d1 = 1e30f, d2v = 1e30f;
    int i0 = 0, i1 = 0, i2 = 0;
    int base = t * 13;
#pragma unroll
    for (int c = 0; c < 12; c++) {
      float d = candd[base + c];
      int id = candi[base + c];
      if (d < d0) {
        d2v = d1; i2 = i1; d1 = d0; i1 = i0; d0 = d; i0 = id;
      } else if (d < d1) {
        d2v = d1; i2 = i1; d1 = d; i1 = id;
      } else if (d < d2v) {
        d2v = d; i2 = id;
      }
    }
    idxb[t] = i0;
    idxb[64 + t] = i1;
    idxb[128 + t] = i2;
  }
  __syncthreads();

  // ---- phase 1c: pos embed, one (query, neighbor) per thread (t<192) ----
  if (t < 192) {
    const int ql = t & 63;
    const int q = qb + ql;
    const float px = xyz1[q * 3], py = xyz1[q * 3 + 1], pz = xyz1[q * 3 + 2];
    const int id = idxb[t];
    float rx = px - xyz2s[id * 3];
    float ry = py - xyz2s[id * 3 + 1];
    float rz = pz - xyz2s[id * 3 + 2];
    float rn = sqrtf(rx * rx + ry * ry + rz * rz);
    float inv = 1.f / fmaxf(rn, 1e-12f);
    float ux = rx * inv, uy = ry * inv, uz = rz * inv;
    const float* L = lrfs + id * 9;
    float a0 = L[0] * ux + L[1] * uy + L[2] * uz;
    float a1 = L[3] * ux + L[4] * uy + L[5] * uz;
    float a2 = L[6] * ux + L[7] * uy + L[8] * uz;
    u16* pd = posb + (t >> 4) * 512 + (t & 15) * 8;
#pragma unroll
    for (int o = 0; o < DPOS; o++) {
      float v = wps[o * 4] * rn + wps[o * 4 + 1] * a0 + wps[o * 4 + 2] * a1 +
                wps[o * 4 + 3] * a2;
      v = v * pss[o] + pbs[o];
      v = (v >= 0.f) ? v : 0.2f * v;  // LeakyReLU(0.2)
      pd[(o >> 3) * 128 + (o & 7)] = f2bf(v);
    }
  }
  __syncthreads();

  // ---- phase 2: H0 = relu((F[idx] + pos.W0pos^T)*s0 + b0) ----
  const int wv = t >> 6, lane = t & 63;
  const int quad = lane >> 4, cc = lane & 15;
  const float* Fr[3];
  u16* Hr[3];
#pragma unroll
  for (int mt = 0; mt < 3; mt++) {
    int rl = wv * 48 + mt * 16 + cc;  // wave's rows: groups 3*wv+mt
    Fr[mt] = F + ((size_t)(b * N2Q + idxb[rl])) * H0Q;
    int jj = rl >> 6, ql = rl & 63;
    Hr[mt] = H0 + ((size_t)(jj * NQ) + qb + ql) * H0Q;
  }
  bf16x8 afr[3];
#pragma unroll
  for (int mt = 0; mt < 3; mt++)
    afr[mt] = *(const bf16x8*)((const char*)posb + (wv * 3 + mt) * 1024 + (lane << 4));
  const f32x4 zf = {};
  for (int n0 = 0; n0 < H0Q; n0 += 128) {
    bf16x8 bfr[8];
#pragma unroll
    for (int nt = 0; nt < 8; nt++)
      bfr[nt] = *(const bf16x8*)(w0p + (n0 + nt * 16 + cc) * 32 + quad * 8);
    f32x4 acc[3][8];
#pragma unroll
    for (int mt = 0; mt < 3; mt++)
#pragma unroll
      for (int nt = 0; nt < 8; nt++)  // swapped operands: C row=h, col=query
        acc[mt][nt] = __builtin_amdgcn_mfma_f32_16x16x32_bf16(bfr[nt], afr[mt],
                                                              zf, 0, 0, 0);
#pragma unroll
    for (int nt = 0; nt < 8; nt++) {
      int hb = n0 + nt * 16 + quad * 4;
      f32x4 sv = *(const f32x4*)(s0 + hb);
      f32x4 bvv = *(const f32x4*)(b0 + hb);
#pragma unroll
      for (int mt = 0; mt < 3; mt++) {
        f32x4 fv = *(const f32x4*)(Fr[mt] + hb);
        u16x4 o4;
#pragma unroll
        for (int r = 0; r < 4; r++) {
          float h = (fv[r] + acc[mt][nt][r]) * sv[r] + bvv[r];
          h = h > 0.f ? h : 0.f;
          o4[r] = f2bf(h);
        }
        *(u16x4*)(Hr[mt] + hb) = o4;
      }
    }
  }
}

// ---------------------------------------------------------------------------
// gemm2: out[b][n][n1] = sum_j relu((H0_j[q][:] . W1[n][:])*s1[n] + b1[n]).
// BM=128 (queries) x BN=256 (H1), BK=64. 512 threads = 8 waves (2M x 4N),
// per-wave C = 64x64 (acc 64 VGPR + sum 64 VGPR). 24 K-tiles (3 planes x 8),
// TRIPLE-buffered (A 16KB + B 32KB per tile = 144 KiB LDS, 1 block/CU).
// Per K-tile: vmcnt(12) [2 tiles of 6 loads stay in flight] -> barrier ->
// 16 ds_read_b128 -> lgkmcnt(0) -> barrier -> stage(kt+3) -> 32 MFMA.
// Tail peels kt 21/22/23 with vmcnt(12/6/0). relu-fold at kt 7/15/23.
// LDS groups: A g = kk*8 + rowgroup (16 per tile); B g = kk*16 + colgroup.
__global__ __launch_bounds__(512, 2) void gemm2(const u16* __restrict__ A,
                                                const u16* __restrict__ W,
                                                const float* __restrict__ s,
                                                const float* __restrict__ bz,
                                                float* __restrict__ out) {
  __shared__ alignas(16) u16 As[3][128 * 64];  // 16 KB per buffer
  __shared__ alignas(16) u16 Bs[3][256 * 64];  // 32 KB per buffer
  const int id = blockIdx.x;            // 512 blocks
  const int xcd = id & 7, g = id >> 3;  // g 0..63
  const int m0 = (xcd * 16 + (g >> 2)) * 128;  // 16 m-tiles per XCD
  const int n0 = (g & 3) * 256;                // 4 consecutive blocks share m0
  const int t = threadIdx.x;
  const int wv = t >> 6, lane = t & 63;
  const int wm = wv >> 2, wn = wv & 3;  // 2M x 4N wave grid
  const int quad = lane >> 4, cc = lane & 15;
  const int lr = lane & 15, lk = (lane >> 4) * 8;  // staging row/k in group

  // staging source offsets (elements; +k0 per K-tile)
  const size_t aOff = (size_t)(m0 + wv * 16 + lr) * 512 + lk;
  const size_t bOff = (size_t)(n0 + wv * 32 + lr) * 512 + lk;

  float sv[4], bv[4];
#pragma unroll
  for (int nt = 0; nt < 4; nt++) {
    int gn = n0 + wn * 64 + nt * 16 + cc;
    sv[nt] = s[gn];
    bv[nt] = bz[gn];
  }

  auto stage = [&](int kt, int bi) {
    const u16* Ap = A + (size_t)(kt >> 3) * ((size_t)NQ * H0Q) + ((kt & 7) << 6);
    const u16* Wp = W + ((kt & 7) << 6);
    char* ab = (char*)As[bi] + (lane << 4);
    char* bb = (char*)Bs[bi] + (lane << 4);
    // A: 2 loads -> groups (kk*8 + wv)
    load16_lds(Ap + aOff, ab + wv * 1024);
    load16_lds(Ap + aOff + 32, ab + (8 + wv) * 1024);
    // B: 4 loads -> groups (kk*16 + wv*2 + half)
    load16_lds(Wp + bOff, bb + (wv * 2) * 1024);
    load16_lds(Wp + bOff + (size_t)16 * 512, bb + (wv * 2 + 1) * 1024);
    load16_lds(Wp + bOff + 32, bb + (16 + wv * 2) * 1024);
    load16_lds(Wp + bOff + (size_t)16 * 512 + 32, bb + (16 + wv * 2 + 1) * 1024);
  };

  f32x4 sum[4][4] = {};
  f32x4 acc[4][4] = {};

  auto tile = [&](int bi, int ktStage) {
    bf16x8 af[2][4], bf[2][4];
    const char* ab = (const char*)As[bi] + (lane << 4);
    const char* bb = (const char*)Bs[bi] + (lane << 4);
#pragma unroll
    for (int kk = 0; kk < 2; kk++)
#pragma unroll
      for (int mt = 0; mt < 4; mt++)
        af[kk][mt] = *(const bf16x8*)(ab + (kk * 8 + wm * 4 + mt) * 1024);
#pragma unroll
    for (int kk = 0; kk < 2; kk++)
#pragma unroll
      for (int nt = 0; nt < 4; nt++)
        bf[kk][nt] = *(const bf16x8*)(bb + (kk * 16 + wn * 4 + nt) * 1024);
    asm volatile("s_waitcnt lgkmcnt(0)" ::: "memory");
    __builtin_amdgcn_s_barrier();
    if (ktStage >= 0) stage(ktStage, bi);
    __builtin_amdgcn_s_setprio(1);
#pragma unroll
    for (int kk = 0; kk < 2; kk++)
#pragma unroll
      for (int mt = 0; mt < 4; mt++)
#pragma unroll
        for (int nt = 0; nt < 4; nt++)
          acc[mt][nt] = __builtin_amdgcn_mfma_f32_16x16x32_bf16(
              af[kk][mt], bf[kk][nt], acc[mt][nt], 0, 0, 0);
    __builtin_amdgcn_s_setprio(0);
  };

  auto fold = [&]() {
#pragma unroll
    for (int mt = 0; mt < 4; mt++)
#pragma unroll
      for (int nt = 0; nt < 4; nt++) {
#pragma unroll
        for (int r = 0; r < 4; r++) {
          float h = acc[mt][nt][r] * sv[nt] + bv[nt];
          sum[mt][nt][r] += (h > 0.f ? h : 0.f);
        }
        acc[mt][nt] = f32x4{};
      }
  };

  stage(0, 0);
  stage(1, 1);
  stage(2, 2);

#pragma unroll 3
  for (int kt = 0; kt < 21; kt++) {
    asm volatile("s_waitcnt vmcnt(12)" ::: "memory");
    __builtin_amdgcn_s_barrier();
    tile(kt % 3, kt + 3);
    if ((kt & 7) == 7) fold();  // kt 7, 15: plane boundary
  }
  asm volatile("s_waitcnt vmcnt(12)" ::: "memory");
  __builtin_amdgcn_s_barrier();
  tile(0, -1);  // kt 21
  asm volatile("s_waitcnt vmcnt(6)" ::: "memory");
  __builtin_amdgcn_s_barrier();
  tile(1, -1);  // kt 22
  asm volatile("s_waitcnt vmcnt(0)" ::: "memory");
  __builtin_amdgcn_s_barrier();
  tile(2, -1);  // kt 23
  fold();

#pragma unroll
  for (int nt = 0; nt < 4; nt++) {
    int gn = n0 + wn * 64 + nt * 16 + cc;
#pragma unroll
    for (int mt = 0; mt < 4; mt++) {
      int gm = m0 + wm * 64 + mt * 16 + quad * 4;
#pragma unroll
      for (int r = 0; r < 4; r++) {
        int q = gm + r;
        out[((size_t)(q >> 11) * H1Q + gn) * N1Q + (q & 2047)] = sum[mt][nt][r];
      }
    }
  }
}

// ---------------------------------------------------------------------------
extern "C" void kernel_launch(void* const* d_in, const int* in_sizes, int n_in,
                              void* d_out, int out_size, void* d_ws,
                              size_t ws_size, hipStream_t stream) {
  const float* xyz1 = (const float*)d_in[0];
  const float* xyz2 = (const float*)d_in[1];
  const float* feat2 = (const float*)d_in[2];
  const float* lrf2 = (const float*)d_in[3];
  const float* w_pos = (const float*)d_in[4];
  const float* pscale = (const float*)d_in[5];
  const float* pbias = (const float*)d_in[6];
  const float* w0 = (const float*)d_in[7];
  const float* s0 = (const float*)d_in[8];
  const float* b0 = (const float*)d_in[9];
  const float* w1 = (const float*)d_in[10];
  const float* s1 = (const float*)d_in[11];
  const float* b1 = (const float*)d_in[12];
  float* out = (float*)d_out;

  char* ws = (char*)d_ws;
  u16* w0f = (u16*)(ws + WS_W0F);
  u16* w0p = (u16*)(ws + WS_W0P);
  u16* w1b = (u16*)(ws + WS_W1);
  u16* f2b = (u16*)(ws + WS_F2B);
  float* F = (float*)(ws + WS_F);
  u16* H0 = (u16*)(ws + WS_H0);

  convert_inputs<<<933888 / 256, 256, 0, stream>>>(w0, w1, feat2, w0f, w0p,
                                                   w1b, f2b);
  fgemm<<<32, 256, 0, stream>>>(f2b, w0f, F);
  build_h0<<<NQ / 64, 256, 0, stream>>>(xyz1, xyz2, lrf2, w_pos, pscale,
                                        pbias, w0p, F, s0, b0, H0);
  gemm2<<<512, 512, 0, stream>>>(H0, w1b, s1, b1, out);
}